// Round 16
// baseline (248.106 us; speedup 1.0000x reference)
//
#include <hip/hip_runtime.h>

// DoReFa dense: out = q_in(3-bit) @ (sign(W)*E) + b,  E = mean|W|
//   out[i,j] = (E/7) * sum_k r[i,k]*sign(W[k,j]),  r in 0..7 -- exact in i8 MFMA.
// R16: B packed 2-bit in LDS (codes 0,1,3 = 0,+1,-1), expanded in-register via
//      v_perm_b32 (SWAR spread + LUT map + byte transpose, ~23 VALU/frag on the
//      VALU pipe). B LDS reads drop 4->1 per lane/chunk; B stage 32KB->8KB/intvl.
//      A path = R7/R8-verified paired-line layout. R14 interval schedule kept:
//      256^2 tile, 16 waves 4x4, BK=128 intervals, 1 barrier+vmcnt(0)/interval.

static constexpr int BATCH  = 8192;
static constexpr int IN_CH  = 4096;
static constexpr int NUNITS = 4096;
static constexpr int TPB    = 256;

typedef int v4i __attribute__((ext_vector_type(4)));

// ---- workspace layout ----
static constexpr size_t A8_OFF   = 0;
static constexpr size_t A8_BYTES = (size_t)BATCH * IN_CH;        // 32 MB
static constexpr size_t PB_OFF   = A8_OFF + A8_BYTES;            // packed B
static constexpr size_t PB_BYTES = (size_t)NUNITS * IN_CH / 4;   // 4 MB
static constexpr int    NPART    = 4096;
static constexpr size_t PART_OFF = PB_OFF + PB_BYTES;
static constexpr size_t SCALE_OFF= PART_OFF + NPART * sizeof(float);

// -------------------------- sign(W) -> packed 2-bit B + fused |W| partial sum
// PB dword index: bCol*65536 + kt*1024 + wc*256 + lane*4 + n, where
//   col = bCol*256 + wc*64 + n*16 + (lane&15), quarter lk4 = lane>>4, kt = k/64;
//   dword = sum_j (sign(W[kt*64 + lk4*16 + j][col]) & 3) << (2j)
__global__ __launch_bounds__(TPB) void k_signT(const float* __restrict__ W,
                                               unsigned int* __restrict__ pb,
                                               float* __restrict__ partials) {
    __shared__ char tile[64][68];   // [n_local][k_local]
    __shared__ float red[TPB];
    const int bk = blockIdx.x & 63;      // kt
    const int bn = blockIdx.x >> 6;      // 64-col tile
    const int t  = threadIdx.x;
    const int c4 = (t & 15) * 4;
    const int r0 = t >> 4;
    float asum = 0.f;
#pragma unroll
    for (int i = 0; i < 4; ++i) {
        const int r = i * 16 + r0;       // k_local
        float4 w = *(const float4*)(W + (size_t)(bk * 64 + r) * NUNITS + bn * 64 + c4);
        asum += fabsf(w.x) + fabsf(w.y) + fabsf(w.z) + fabsf(w.w);
        tile[c4 + 0][r] = (w.x > 0.f) ? 1 : ((w.x < 0.f) ? -1 : 0);
        tile[c4 + 1][r] = (w.y > 0.f) ? 1 : ((w.y < 0.f) ? -1 : 0);
        tile[c4 + 2][r] = (w.z > 0.f) ? 1 : ((w.z < 0.f) ? -1 : 0);
        tile[c4 + 3][r] = (w.w > 0.f) ? 1 : ((w.w < 0.f) ? -1 : 0);
    }
    __syncthreads();
    // pack: thread t -> (c_local = t&63, lk4p = t>>6)
    const int cl   = t & 63;
    const int lk4p = t >> 6;
    unsigned int d = 0;
#pragma unroll
    for (int j = 0; j < 16; ++j)
        d |= ((unsigned int)(unsigned char)tile[cl][lk4p * 16 + j] & 3u) << (2 * j);
    const int lanep = lk4p * 16 + (cl & 15);
    const size_t dw = (size_t)(bn >> 2) * 65536 + (size_t)bk * 1024
                    + (size_t)(bn & 3) * 256 + lanep * 4 + (cl >> 4);
    pb[dw] = d;

    red[t] = asum;
    __syncthreads();
    for (int off = TPB / 2; off > 0; off >>= 1) {
        if (t < off) red[t] += red[t + off];
        __syncthreads();
    }
    if (t == 0) partials[blockIdx.x] = red[0];
}

// ------------------------------------------------------------- quantize A (+ fused scale)
__device__ __forceinline__ unsigned int q4(float4 v) {
    unsigned int b0 = (unsigned int)(int)rintf(fminf(1.0f, fabsf(v.x)) * 7.0f);
    unsigned int b1 = (unsigned int)(int)rintf(fminf(1.0f, fabsf(v.y)) * 7.0f);
    unsigned int b2 = (unsigned int)(int)rintf(fminf(1.0f, fabsf(v.z)) * 7.0f);
    unsigned int b3 = (unsigned int)(int)rintf(fminf(1.0f, fabsf(v.w)) * 7.0f);
    return b0 | (b1 << 8) | (b2 << 16) | (b3 << 24);
}

__global__ __launch_bounds__(TPB) void k_quant_a(const float4* __restrict__ x4,
                                                 uint4* __restrict__ a16,
                                                 const float* __restrict__ partials,
                                                 float* __restrict__ scale) {
    if (blockIdx.x == 0) {
        __shared__ float red[TPB];
        float s = 0.f;
        for (int i = threadIdx.x; i < NPART; i += TPB) s += partials[i];
        red[threadIdx.x] = s;
        __syncthreads();
        for (int off = TPB / 2; off > 0; off >>= 1) {
            if ((int)threadIdx.x < off) red[threadIdx.x] += red[threadIdx.x + off];
            __syncthreads();
        }
        if (threadIdx.x == 0) {
            float E = red[0] / (float)((size_t)IN_CH * NUNITS);
            *scale = E / 7.0f;
        }
    }
    const size_t t = (size_t)blockIdx.x * TPB + threadIdx.x;
    uint4 o;
    o.x = q4(x4[t * 4 + 0]);
    o.y = q4(x4[t * 4 + 1]);
    o.z = q4(x4[t * 4 + 2]);
    o.w = q4(x4[t * 4 + 3]);
    a16[t] = o;
}

// ---------------------------------------------------------------- GEMM
// 256x256 tile, interval BK=128 (2 chunks of 64), 16 waves (4x4, 64x64),
// mfma_i32_16x16x64_i8. A: 2 buf x 2 chunk x [128 lines x 128B], line L =
// A-row L || A-row L+128, phys slot = logical ^ (L&7). B: 2 buf x 2 chunk x 4KB
// packed 2-bit, one ds_read_b128/lane/chunk, v_perm expansion.
__device__ __forceinline__ void gload_lds16(const void* g, void* l) {
    __builtin_amdgcn_global_load_lds((const __attribute__((address_space(1))) void*)g,
                                     (__attribute__((address_space(3))) void*)l,
                                     16, 0, 0);
}
__device__ __forceinline__ void gload_lds4(const void* g, void* l) {
    __builtin_amdgcn_global_load_lds((const __attribute__((address_space(1))) void*)g,
                                     (__attribute__((address_space(3))) void*)l,
                                     4, 0, 0);
}

__device__ __forceinline__ unsigned int vperm(unsigned int s0, unsigned int s1,
                                              unsigned int sel) {
    unsigned int d;
    asm("v_perm_b32 %0, %1, %2, %3" : "=v"(d) : "v"(s0), "v"(s1), "v"(sel));
    return d;
}

// expand 16 x 2-bit codes (0,1,3) -> 16 x i8 (0,+1,-1)
__device__ __forceinline__ v4i expand2b(unsigned int p, unsigned int lut) {
    const unsigned int M = 0x03030303u;
    unsigned int t0 = p & M;
    unsigned int t1 = (p >> 2) & M;
    unsigned int t2 = (p >> 4) & M;
    unsigned int t3 = (p >> 6) & M;
    t0 = vperm(lut, lut, t0);
    t1 = vperm(lut, lut, t1);
    t2 = vperm(lut, lut, t2);
    t3 = vperm(lut, lut, t3);
    v4i b;
    unsigned int q, r;
    q = vperm(t1, t0, 0x0C0C0400u); r = vperm(t3, t2, 0x0C0C0400u);
    b[0] = (int)vperm(r, q, 0x05040100u);
    q = vperm(t1, t0, 0x0C0C0501u); r = vperm(t3, t2, 0x0C0C0501u);
    b[1] = (int)vperm(r, q, 0x05040100u);
    q = vperm(t1, t0, 0x0C0C0602u); r = vperm(t3, t2, 0x0C0C0602u);
    b[2] = (int)vperm(r, q, 0x05040100u);
    q = vperm(t1, t0, 0x0C0C0703u); r = vperm(t3, t2, 0x0C0C0703u);
    b[3] = (int)vperm(r, q, 0x05040100u);
    return b;
}

#define VMCNT0   asm volatile("s_waitcnt vmcnt(0)" ::: "memory")
#define LGKM0    asm volatile("s_waitcnt lgkmcnt(0)" ::: "memory")
#define SCHEDB   __builtin_amdgcn_sched_barrier(0)
#define BARRIER  __builtin_amdgcn_s_barrier()
#define PRIO1    __builtin_amdgcn_s_setprio(1)
#define PRIO0    __builtin_amdgcn_s_setprio(0)

static constexpr int NI = IN_CH / 128;   // 32 intervals

__global__ __launch_bounds__(1024, 4) void k_gemm(const char* __restrict__ A8,
                                                  const unsigned int* __restrict__ PB,
                                                  const float* __restrict__ scale_p,
                                                  const float* __restrict__ bias,
                                                  float* __restrict__ out) {
    __shared__ char As[2][32768];   // 64 KiB: [buf][chunk 16KB x2]
    __shared__ char Ps[2][8192];    // 16 KiB: [buf][chunk 4KB x2]

    const int t    = threadIdx.x;                 // 0..1023
    const int bid  = blockIdx.x;                  // 512 blocks
    const int swzb = (bid & 7) * 64 + (bid >> 3); // XCD swizzle (bijective)
    const int bRow = swzb >> 4;                   // 0..31
    const int bCol = swzb & 15;                   // 0..15
    const int lane = t & 63;
    const int wid  = t >> 6;                      // 0..15
    const int wr   = wid >> 2;                    // 0..3
    const int wc   = wid & 3;                     // 0..3
    const int lr   = lane & 15;
    const int lk4  = lane >> 4;                   // 0..3

    // A frag read offsets (per m, within a 16KB chunk)
    int aoff0, aoff1, aoff2, aoff3;
    {
        const int r0_ = wr * 64 + 0 * 16 + lr, l0 = r0_ & 127;
        const int r1_ = wr * 64 + 1 * 16 + lr, l1 = r1_ & 127;
        const int r2_ = wr * 64 + 2 * 16 + lr, l2 = r2_ & 127;
        const int r3_ = wr * 64 + 3 * 16 + lr, l3 = r3_ & 127;
        aoff0 = l0 * 128 + (((((r0_ >> 7) << 2) | lk4) ^ (l0 & 7)) << 4);
        aoff1 = l1 * 128 + (((((r1_ >> 7) << 2) | lk4) ^ (l1 & 7)) << 4);
        aoff2 = l2 * 128 + (((((r2_ >> 7) << 2) | lk4) ^ (l2 & 7)) << 4);
        aoff3 = l3 * 128 + (((((r3_ >> 7) << 2) | lk4) ^ (l3 & 7)) << 4);
    }
    const int pboff = wc * 1024 + lane * 16;      // B packed read (within 4KB chunk)

    // A staging: thread t -> dest line t>>3, phys slot t&7 (linear dest t*16)
    const int s_log   = (t & 7) ^ ((t >> 3) & 7);
    const int rowbase = ((s_log >> 2) << 7) + (t >> 3);
    const char* sA    = A8 + (size_t)(bRow * 256 + rowbase) * IN_CH + ((s_log & 3) << 4);
    // B staging: thread t stages dword t of each chunk
    const unsigned int* pbg = PB + (size_t)bCol * 65536 + t;

    const unsigned int lut = 0xFF000100u;   // code 0->0x00, 1->0x01, 3->0xFF

    v4i acc[4][4] = {};

#define STAGE(P, BI)                                                             \
    do {                                                                         \
        gload_lds16(sA + (size_t)(P) * 128 +  0, &As[BI][0]     + t * 16);       \
        gload_lds16(sA + (size_t)(P) * 128 + 64, &As[BI][16384] + t * 16);       \
        gload_lds4(pbg + (size_t)(P) * 2048,        &Ps[BI][0]    + t * 4);      \
        gload_lds4(pbg + (size_t)(P) * 2048 + 1024, &Ps[BI][4096] + t * 4);      \
    } while (0)

#define CHUNK(BI, c)                                                             \
    do {                                                                         \
        const char* _ap = &As[BI][(c) * 16384];                                  \
        v4i a0 = *(const v4i*)(_ap + aoff0);                                     \
        v4i a1 = *(const v4i*)(_ap + aoff1);                                     \
        v4i a2 = *(const v4i*)(_ap + aoff2);                                     \
        v4i a3 = *(const v4i*)(_ap + aoff3);                                     \
        v4i bp = *(const v4i*)(&Ps[BI][(c) * 4096] + pboff);                     \
        _Pragma("unroll") for (int n = 0; n < 4; ++n) {                          \
            v4i b = expand2b((unsigned int)bp[n], lut);                          \
            PRIO1;                                                               \
            acc[0][n] = __builtin_amdgcn_mfma_i32_16x16x64_i8(a0, b, acc[0][n], 0, 0, 0); \
            acc[1][n] = __builtin_amdgcn_mfma_i32_16x16x64_i8(a1, b, acc[1][n], 0, 0, 0); \
            acc[2][n] = __builtin_amdgcn_mfma_i32_16x16x64_i8(a2, b, acc[2][n], 0, 0, 0); \
            acc[3][n] = __builtin_amdgcn_mfma_i32_16x16x64_i8(a3, b, acc[3][n], 0, 0, 0); \
            PRIO0;                                                               \
        }                                                                        \
    } while (0)

#define INTERVAL(P, CUR, STG, DOSTG)                                             \
    do {                                                                         \
        SCHEDB; LGKM0;                                                           \
        VMCNT0;                                                                  \
        BARRIER; SCHEDB;                                                         \
        if (DOSTG) { STAGE((P) + 1, STG); }                                      \
        CHUNK(CUR, 0);                                                           \
        CHUNK(CUR, 1);                                                           \
    } while (0)

    // prologue: stage interval 0
    STAGE(0, 0);

    for (int P = 0; P < NI - 2; P += 2) {
        INTERVAL(P,     0, 1, 1);
        INTERVAL(P + 1, 1, 0, 1);
    }
    INTERVAL(NI - 2, 0, 1, 1);   // P=30: stages 31
    INTERVAL(NI - 1, 1, 0, 0);   // P=31: compute only

    // ---- epilogue
    const float scale = *scale_p;
    const int orow0 = bRow * 256 + wr * 64;
    const int ocol0 = bCol * 256 + wc * 64;
#pragma unroll
    for (int m = 0; m < 4; ++m) {
#pragma unroll
        for (int n = 0; n < 4; ++n) {
            const int col = ocol0 + n * 16 + lr;
            const float bb = bias[col];
            const int rbase = orow0 + m * 16 + lk4 * 4;
#pragma unroll
            for (int j = 0; j < 4; ++j)
                out[(size_t)(rbase + j) * NUNITS + col] = scale * (float)acc[m][n][j] + bb;
        }
    }
#undef STAGE
#undef CHUNK
#undef INTERVAL
}

// ---------------------------------------------------------------- launch
extern "C" void kernel_launch(void* const* d_in, const int* in_sizes, int n_in,
                              void* d_out, int out_size, void* d_ws, size_t ws_size,
                              hipStream_t stream) {
    const float* x  = (const float*)d_in[0];
    const float* W  = (const float*)d_in[1];
    const float* b  = (const float*)d_in[2];
    float* out      = (float*)d_out;

    char*  ws       = (char*)d_ws;
    char*  A8       = ws + A8_OFF;
    unsigned int* PB = (unsigned int*)(ws + PB_OFF);
    float* partials = (float*)(ws + PART_OFF);
    float* scale    = (float*)(ws + SCALE_OFF);

    k_signT<<<(IN_CH / 64) * (NUNITS / 64), TPB, 0, stream>>>(W, PB, partials);
    k_quant_a<<<(BATCH * (IN_CH / 16)) / TPB, TPB, 0, stream>>>((const float4*)x, (uint4*)A8,
                                                                partials, scale);
    k_gemm<<<(BATCH / 256) * (NUNITS / 256), 1024, 0, stream>>>(A8, PB, scale, b, out);
}

// Round 17
// 168.518 us; speedup vs baseline: 1.4723x; 1.4723x over previous
//
#include <hip/hip_runtime.h>

// DoReFa dense: out = q_in(3-bit) @ (sign(W)*E) + b,  E = mean|W|
//   out[i,j] = (E/7) * sum_k r[i,k]*sign(W[k,j]),  r in 0..7 -- exact in i8 MFMA.
// R17 = revert to R15 champion (best measured: total 166.7us, gemm 114.9us).
//   GEMM: 256^2 tile, 16 waves (4x4, 64x64 wave tiles), BK=128 sync intervals,
//   2 x 64KB LDS buffers, A64||B64 lines + 8-slot XOR swizzle (conflict-free),
//   global_load_lds staging 1 interval ahead, 1 barrier + vmcnt(0) per interval,
//   setprio around MFMA clusters, XCD-aware block swizzle.
//   R16's 2-bit-B experiment removed (VALU expansion became the serial pipe).

static constexpr int BATCH  = 8192;
static constexpr int IN_CH  = 4096;
static constexpr int NUNITS = 4096;
static constexpr int TPB    = 256;

typedef int v4i __attribute__((ext_vector_type(4)));

// ---- workspace layout ----
static constexpr size_t A8_OFF   = 0;
static constexpr size_t A8_BYTES = (size_t)BATCH * IN_CH;    // 32 MB
static constexpr size_t BT_OFF   = A8_OFF + A8_BYTES;
static constexpr size_t BT_BYTES = (size_t)NUNITS * IN_CH;   // 16 MB
static constexpr int    NPART    = 4096;
static constexpr size_t PART_OFF = BT_OFF + BT_BYTES;
static constexpr size_t SCALE_OFF= PART_OFF + NPART * sizeof(float);

// -------------------------- sign(W) transpose to [N][K]  +  fused |W| partial sum
__global__ __launch_bounds__(TPB) void k_signT(const float* __restrict__ W,
                                               char* __restrict__ bt,
                                               float* __restrict__ partials) {
    __shared__ char tile[64][68];   // [n][k], +4 pad
    __shared__ float red[TPB];
    const int bk = blockIdx.x & 63;
    const int bn = blockIdx.x >> 6;
    const int t  = threadIdx.x;
    const int c4 = (t & 15) * 4;
    const int r0 = t >> 4;
    float asum = 0.f;
#pragma unroll
    for (int i = 0; i < 4; ++i) {
        const int r = i * 16 + r0;
        float4 w = *(const float4*)(W + (size_t)(bk * 64 + r) * NUNITS + bn * 64 + c4);
        asum += fabsf(w.x) + fabsf(w.y) + fabsf(w.z) + fabsf(w.w);
        tile[c4 + 0][r] = (w.x > 0.f) ? 1 : ((w.x < 0.f) ? -1 : 0);
        tile[c4 + 1][r] = (w.y > 0.f) ? 1 : ((w.y < 0.f) ? -1 : 0);
        tile[c4 + 2][r] = (w.z > 0.f) ? 1 : ((w.z < 0.f) ? -1 : 0);
        tile[c4 + 3][r] = (w.w > 0.f) ? 1 : ((w.w < 0.f) ? -1 : 0);
    }
    __syncthreads();
    const int n  = t >> 2;
    const int kk = (t & 3) * 16;
    char o[16];
#pragma unroll
    for (int j = 0; j < 16; ++j) o[j] = tile[n][kk + j];
    *(uint4*)(bt + (size_t)(bn * 64 + n) * IN_CH + bk * 64 + kk) = *(const uint4*)o;

    red[t] = asum;
    __syncthreads();
    for (int off = TPB / 2; off > 0; off >>= 1) {
        if (t < off) red[t] += red[t + off];
        __syncthreads();
    }
    if (t == 0) partials[blockIdx.x] = red[0];
}

// ------------------------------------------------------------- quantize A (+ fused scale)
__device__ __forceinline__ unsigned int q4(float4 v) {
    unsigned int b0 = (unsigned int)(int)rintf(fminf(1.0f, fabsf(v.x)) * 7.0f);
    unsigned int b1 = (unsigned int)(int)rintf(fminf(1.0f, fabsf(v.y)) * 7.0f);
    unsigned int b2 = (unsigned int)(int)rintf(fminf(1.0f, fabsf(v.z)) * 7.0f);
    unsigned int b3 = (unsigned int)(int)rintf(fminf(1.0f, fabsf(v.w)) * 7.0f);
    return b0 | (b1 << 8) | (b2 << 16) | (b3 << 24);
}

__global__ __launch_bounds__(TPB) void k_quant_a(const float4* __restrict__ x4,
                                                 uint4* __restrict__ a16,
                                                 const float* __restrict__ partials,
                                                 float* __restrict__ scale) {
    if (blockIdx.x == 0) {
        __shared__ float red[TPB];
        float s = 0.f;
        for (int i = threadIdx.x; i < NPART; i += TPB) s += partials[i];
        red[threadIdx.x] = s;
        __syncthreads();
        for (int off = TPB / 2; off > 0; off >>= 1) {
            if ((int)threadIdx.x < off) red[threadIdx.x] += red[threadIdx.x + off];
            __syncthreads();
        }
        if (threadIdx.x == 0) {
            float E = red[0] / (float)((size_t)IN_CH * NUNITS);
            *scale = E / 7.0f;
        }
    }
    const size_t t = (size_t)blockIdx.x * TPB + threadIdx.x;
    uint4 o;
    o.x = q4(x4[t * 4 + 0]);
    o.y = q4(x4[t * 4 + 1]);
    o.z = q4(x4[t * 4 + 2]);
    o.w = q4(x4[t * 4 + 3]);
    a16[t] = o;
}

// ---------------------------------------------------------------- GEMM (champion)
__device__ __forceinline__ void gload_lds16(const void* g, void* l) {
    __builtin_amdgcn_global_load_lds((const __attribute__((address_space(1))) void*)g,
                                     (__attribute__((address_space(3))) void*)l,
                                     16, 0, 0);
}

#define VMCNT0   asm volatile("s_waitcnt vmcnt(0)" ::: "memory")
#define LGKM0    asm volatile("s_waitcnt lgkmcnt(0)" ::: "memory")
#define SCHEDB   __builtin_amdgcn_sched_barrier(0)
#define BARRIER  __builtin_amdgcn_s_barrier()
#define PRIO1    __builtin_amdgcn_s_setprio(1)
#define PRIO0    __builtin_amdgcn_s_setprio(0)

static constexpr int NI = IN_CH / 128;   // 32 intervals

__global__ __launch_bounds__(1024, 4) void k_gemm(const char* __restrict__ A8,
                                                  const char* __restrict__ BT,
                                                  const float* __restrict__ scale_p,
                                                  const float* __restrict__ bias,
                                                  float* __restrict__ out) {
    __shared__ char Ms[2][65536];   // 128 KiB

    const int t    = threadIdx.x;                 // 0..1023
    const int bid  = blockIdx.x;                  // 512 blocks
    const int swzb = (bid & 7) * 64 + (bid >> 3); // XCD swizzle (bijective: 512%8==0)
    const int bRow = swzb >> 4;                   // 0..31
    const int bCol = swzb & 15;                   // 0..15
    const int lane = t & 63;
    const int wid  = t >> 6;                      // 0..15
    const int wr   = wid >> 2;                    // 0..3
    const int wc   = wid & 3;                     // 0..3
    const int lr   = lane & 15;
    const int lk4  = lane >> 4;                   // 0..3

    const int aoff = ((lk4 ^ (lr & 7)) << 4);     // A logical slots 0..3
    const int boff = aoff ^ 64;                   // B logical slots 4..7

    const int lslot = (t & 7) ^ ((t >> 3) & 7);
    const char* mbase = (lslot < 4)
        ? (A8 + (size_t)(bRow * 256) * IN_CH)
        : (BT + (size_t)(bCol * 256) * IN_CH);
    const char* sbase = mbase + (size_t)(t >> 3) * IN_CH + ((lslot & 3) << 4);

    v4i acc[4][4] = {};

#define STAGE4(P, STG)                                                           \
    _Pragma("unroll") for (int c = 0; c < 2; ++c)                                \
        _Pragma("unroll") for (int h = 0; h < 2; ++h)                            \
            gload_lds16(sbase + (size_t)h * 128 * IN_CH + ((size_t)(P) * 128 + c * 64), \
                        (STG) + c * 32768 + h * 16384 + t * 16)

#define CHUNK(CUR, c)                                                            \
    do {                                                                         \
        const char* _cp = (CUR) + (c) * 32768;                                   \
        v4i a_[4], b_[4];                                                        \
        _Pragma("unroll") for (int m = 0; m < 4; ++m)                            \
            a_[m] = *(const v4i*)(_cp + (wr * 64 + m * 16 + lr) * 128 + aoff);   \
        _Pragma("unroll") for (int n = 0; n < 4; ++n)                            \
            b_[n] = *(const v4i*)(_cp + (wc * 64 + n * 16 + lr) * 128 + boff);   \
        PRIO1;                                                                   \
        _Pragma("unroll") for (int m = 0; m < 4; ++m)                            \
            _Pragma("unroll") for (int n = 0; n < 4; ++n)                        \
                acc[m][n] = __builtin_amdgcn_mfma_i32_16x16x64_i8(               \
                    a_[m], b_[n], acc[m][n], 0, 0, 0);                           \
        PRIO0;                                                                   \
    } while (0)

#define INTERVAL(P, CUR, STG, DOSTG)                                             \
    do {                                                                         \
        SCHEDB; LGKM0;                                                           \
        VMCNT0;                                                                  \
        BARRIER; SCHEDB;                                                         \
        if (DOSTG) { STAGE4((P) + 1, STG); }                                     \
        CHUNK(CUR, 0);                                                           \
        CHUNK(CUR, 1);                                                           \
    } while (0)

    char* B0 = (char*)Ms[0];
    char* B1 = (char*)Ms[1];

    STAGE4(0, B0);

    for (int P = 0; P < NI - 2; P += 2) {
        INTERVAL(P,     B0, B1, 1);
        INTERVAL(P + 1, B1, B0, 1);
    }
    INTERVAL(NI - 2, B0, B1, 1);   // P=30: stages 31
    INTERVAL(NI - 1, B1, B0, 0);   // P=31: compute only

    // ---- epilogue
    const float scale = *scale_p;
    const int orow0 = bRow * 256 + wr * 64;
    const int ocol0 = bCol * 256 + wc * 64;
#pragma unroll
    for (int m = 0; m < 4; ++m) {
#pragma unroll
        for (int n = 0; n < 4; ++n) {
            const int col = ocol0 + n * 16 + lr;
            const float bb = bias[col];
            const int rbase = orow0 + m * 16 + lk4 * 4;
#pragma unroll
            for (int j = 0; j < 4; ++j)
                out[(size_t)(rbase + j) * NUNITS + col] = scale * (float)acc[m][n][j] + bb;
        }
    }
#undef STAGE4
#undef CHUNK
#undef INTERVAL
}

// ---------------------------------------------------------------- launch
extern "C" void kernel_launch(void* const* d_in, const int* in_sizes, int n_in,
                              void* d_out, int out_size, void* d_ws, size_t ws_size,
                              hipStream_t stream) {
    const float* x  = (const float*)d_in[0];
    const float* W  = (const float*)d_in[1];
    const float* b  = (const float*)d_in[2];
    float* out      = (float*)d_out;

    char*  ws       = (char*)d_ws;
    char*  A8       = ws + A8_OFF;
    char*  BT       = ws + BT_OFF;
    float* partials = (float*)(ws + PART_OFF);
    float* scale    = (float*)(ws + SCALE_OFF);

    k_signT<<<(IN_CH / 64) * (NUNITS / 64), TPB, 0, stream>>>(W, BT, partials);
    k_quant_a<<<(BATCH * (IN_CH / 16)) / TPB, TPB, 0, stream>>>((const float4*)x, (uint4*)A8,
                                                                partials, scale);
    k_gemm<<<(BATCH / 256) * (NUNITS / 256), 1024, 0, stream>>>(A8, BT, scale, b, out);
}